// Round 4
// baseline (42.717 us; speedup 1.0000x reference)
//
#include <hip/hip_runtime.h>
#include <math.h>

namespace {

constexpr int kNB     = 16;
constexpr int kFrame  = 2048;
constexpr int kChunk  = 32;    // samples per lane; 64 lanes * 32 = 2048
constexpr int kWPB    = 4;     // channels (waves) per 256-thread main block
constexpr int kPairs  = 8;     // 16 bands as 8 cascaded pairs
constexpr int kPS     = 96;    // floats per pair block in ws / LDS
// pair block layout (floats):
// [0..4]  b0_1 b1_1 b2_1 na1_1 na2_1      (band 2p,   gains folded)
// [5..9]  b0_2 b1_2 b2_2 na1_2 na2_2      (band 2p+1, gains folded)
// [10,11] g2_1 g2_2                        (coupling: g2 = (b1_2-a1_2*b0_2, b2_2-a2_2*b0_2))
// [12+12j+k], j=0..5: level j = M^(2^j), M = T^32:
//    k: 0=al1 1=be1 2=ga1  3=al2 4=be2 5=ga2  6=S00 7=S01 8=S10 9=S11  10,11=pad

// ---------------- coefficient kernel: one thread per (channel, pair) ----------------
__global__ __launch_bounds__(256)
void coef_kernel(const float* __restrict__ params, float* __restrict__ ws)
{
    const int job = blockIdx.x * 256 + threadIdx.x;   // 0 .. 2048*8-1
    if (job >= 2048 * kPairs) return;
    const int p  = job & 7;
    const int ch = job >> 3;
    const int bb = ch >> 7;
    const int ff = ch & 127;
    const float* pb = params + (size_t)bb * (50 * 128) + ff;

    const double PI   = 3.14159265358979323846;
    const double SR   = 96000.0;
    const double LN10 = 2.302585092994046;

    double B0[2], B1[2], B2[2], Ac1[2], Ac2[2];

    #pragma unroll
    for (int h = 0; h < 2; ++h) {
        const int band = 2 * p + h;
        const double fn = (double)pb[(band * 3 + 0) * 128];
        const double gn = (double)pb[(band * 3 + 1) * 128];
        const double qn = (double)pb[(band * 3 + 2) * 128];
        const double Q  = exp(log(0.5) + qn * (log(16.0) - log(0.5)));
        double b0, b1, b2, a0, a1, a2;
        if (band == 0) {                       // HPF [20,500] log
            const double fc = exp(log(20.0) + fn * (log(500.0) - log(20.0)));
            const double w0 = 2.0 * PI * fc / SR;
            const double al = sin(w0) / (2.0 * Q);
            const double c  = cos(w0);
            b0 = (1.0 + c) * 0.5; b1 = -(1.0 + c); b2 = (1.0 + c) * 0.5;
            a0 = 1.0 + al; a1 = -2.0 * c; a2 = 1.0 - al;
        } else if (band == kNB - 1) {          // LPF [5000,20000] log
            const double fc = exp(log(5000.0) + fn * (log(20000.0) - log(5000.0)));
            const double w0 = 2.0 * PI * fc / SR;
            const double al = sin(w0) / (2.0 * Q);
            const double c  = cos(w0);
            b0 = (1.0 - c) * 0.5; b1 = 1.0 - c; b2 = (1.0 - c) * 0.5;
            a0 = 1.0 + al; a1 = -2.0 * c; a2 = 1.0 - al;
        } else if (band == 1) {                // low shelf
            const double fc = exp(log(50.0) + fn * (log(16000.0) - log(50.0)));
            const double g  = -24.0 + gn * 48.0;
            const double A  = exp(g * (LN10 / 40.0));
            const double w0 = 2.0 * PI * fc / SR;
            const double al = sin(w0) / (2.0 * Q);
            const double c  = cos(w0);
            const double s2 = 2.0 * sqrt(A) * al;
            b0 = A * ((A + 1.0) - (A - 1.0) * c + s2);
            b1 = 2.0 * A * ((A - 1.0) - (A + 1.0) * c);
            b2 = A * ((A + 1.0) - (A - 1.0) * c - s2);
            a0 = (A + 1.0) + (A - 1.0) * c + s2;
            a1 = -2.0 * ((A - 1.0) + (A + 1.0) * c);
            a2 = (A + 1.0) + (A - 1.0) * c - s2;
        } else if (band == kNB - 2) {          // high shelf
            const double fc = exp(log(50.0) + fn * (log(16000.0) - log(50.0)));
            const double g  = -24.0 + gn * 48.0;
            const double A  = exp(g * (LN10 / 40.0));
            const double w0 = 2.0 * PI * fc / SR;
            const double al = sin(w0) / (2.0 * Q);
            const double c  = cos(w0);
            const double s2 = 2.0 * sqrt(A) * al;
            b0 = A * ((A + 1.0) + (A - 1.0) * c + s2);
            b1 = -2.0 * A * ((A - 1.0) + (A + 1.0) * c);
            b2 = A * ((A + 1.0) + (A - 1.0) * c - s2);
            a0 = (A + 1.0) - (A - 1.0) * c + s2;
            a1 = 2.0 * ((A - 1.0) - (A + 1.0) * c);
            a2 = (A + 1.0) - (A - 1.0) * c - s2;
        } else {                               // peaking [100,15000]
            const double fc = exp(log(100.0) + fn * (log(15000.0) - log(100.0)));
            const double g  = -24.0 + gn * 48.0;
            const double A  = exp(g * (LN10 / 40.0));
            const double w0 = 2.0 * PI * fc / SR;
            const double al = sin(w0) / (2.0 * Q);
            const double c  = cos(w0);
            b0 = 1.0 + al * A; b1 = -2.0 * c; b2 = 1.0 - al * A;
            a0 = 1.0 + al / A; a1 = -2.0 * c; a2 = 1.0 - al / A;
        }
        const double inv = 1.0 / a0;
        b0 *= inv; b1 *= inv; b2 *= inv; a1 *= inv; a2 *= inv;
        if (band == 0) {
            const double in_g = exp((-60.0 + (double)pb[48 * 128] * 60.0) * (LN10 / 20.0));
            b0 *= in_g; b1 *= in_g; b2 *= in_g;
        }
        if (band == kNB - 1) {
            const double out_g = exp((-60.0 + (double)pb[49 * 128] * 60.0) * (LN10 / 20.0));
            b0 *= out_g; b1 *= out_g; b2 *= out_g;
        }
        B0[h] = b0; B1[h] = b1; B2[h] = b2; Ac1[h] = a1; Ac2[h] = a2;
    }

    const double g2_1 = B1[1] - Ac1[1] * B0[1];
    const double g2_2 = B2[1] - Ac2[1] * B0[1];

    float* W = ws + (size_t)job * kPS;
    W[0] = (float)B0[0]; W[1] = (float)B1[0]; W[2] = (float)B2[0];
    W[3] = (float)(-Ac1[0]); W[4] = (float)(-Ac2[0]);
    W[5] = (float)B0[1]; W[6] = (float)B1[1]; W[7] = (float)B2[1];
    W[8] = (float)(-Ac1[1]); W[9] = (float)(-Ac2[1]);
    W[10] = (float)g2_1; W[11] = (float)g2_2;

    // T = [[A1,0],[g2*e1^T,A2]], A_h = [[-a1_h,1],[-a2_h,0]].
    // Track T^k as: diag CH pairs (al,be) per band + full 2x2 S. 10 doublings:
    // after doubling i (i=1..10) we hold T^(2^i); store i=5..10 -> M^(2^j), M=T^32.
    const double a11 = Ac1[0], a21 = Ac2[0], a12 = Ac1[1], a22 = Ac2[1];
    double al1 = 1.0, be1 = 0.0, al2 = 1.0, be2 = 0.0;
    double S00 = g2_1, S01 = 0.0, S10 = g2_2, S11 = 0.0;
    #pragma unroll
    for (int i = 1; i <= 10; ++i) {
        // materialize A1^k, A2^k as 2x2 (from OLD al/be)
        const double P00 = be1 - a11 * al1, P01 = al1, P10 = -a21 * al1, P11 = be1;
        const double Q00 = be2 - a12 * al2, Q01 = al2, Q10 = -a22 * al2, Q11 = be2;
        // S_2k = A2^k * S_k + S_k * A1^k
        const double nS00 = Q00 * S00 + Q01 * S10 + S00 * P00 + S01 * P10;
        const double nS01 = Q00 * S01 + Q01 * S11 + S00 * P01 + S01 * P11;
        const double nS10 = Q10 * S00 + Q11 * S10 + S10 * P00 + S11 * P10;
        const double nS11 = Q10 * S01 + Q11 * S11 + S10 * P01 + S11 * P11;
        S00 = nS00; S01 = nS01; S10 = nS10; S11 = nS11;
        // CH doubling of diagonals
        const double nal1 = al1 * (2.0 * be1 - a11 * al1);
        const double nbe1 = be1 * be1 - a21 * (al1 * al1);
        const double nal2 = al2 * (2.0 * be2 - a12 * al2);
        const double nbe2 = be2 * be2 - a22 * (al2 * al2);
        al1 = nal1; be1 = nbe1; al2 = nal2; be2 = nbe2;
        if (i >= 5) {
            const int j = i - 5;
            float* L = W + 12 + 12 * j;
            L[0] = (float)al1; L[1] = (float)be1; L[2] = (float)(-a21 * al1);
            L[3] = (float)al2; L[4] = (float)be2; L[5] = (float)(-a22 * al2);
            L[6] = (float)S00; L[7] = (float)S01; L[8] = (float)S10; L[9] = (float)S11;
            L[10] = 0.f; L[11] = 0.f;
        }
    }
}

// ---------------- main kernel: 1 wave per channel, pair-fused cascade ----------------
__global__ __launch_bounds__(256)
void biquad_main(const float* __restrict__ audio, const float* __restrict__ ws,
                 float* __restrict__ out)
{
    __shared__ float sP[kWPB * kPairs * kPS];   // 3072 floats = 12 KiB

    const int tid  = threadIdx.x;
    const int wv   = tid >> 6;
    const int lane = tid & 63;
    const int ch   = blockIdx.x * kWPB + wv;

    // cooperative coalesced fill of all 4 channels' pair blocks
    {
        const float4* src = reinterpret_cast<const float4*>(
            ws + (size_t)blockIdx.x * kWPB * kPairs * kPS);
        float4* dst = reinterpret_cast<float4*>(sP);
        constexpr int n4 = kWPB * kPairs * kPS / 4;   // 768
        #pragma unroll
        for (int i = 0; i < n4 / 256; ++i) dst[tid + 256 * i] = src[tid + 256 * i];
    }
    __syncthreads();   // only block-wide sync; waves drift freely afterwards

    const float* Pch = sP + wv * (kPairs * kPS);

    float x[kChunk];
    {
        const float4* ap = reinterpret_cast<const float4*>(
            audio + (size_t)ch * kFrame + lane * kChunk);
        #pragma unroll
        for (int k = 0; k < kChunk / 4; ++k) {
            const float4 v = ap[k];
            x[4 * k + 0] = v.x; x[4 * k + 1] = v.y;
            x[4 * k + 2] = v.z; x[4 * k + 3] = v.w;
        }
    }

    for (int p = 0; p < kPairs; ++p) {
        const float* C = Pch + p * kPS;
        const float b01 = C[0], b11 = C[1], b21 = C[2], na11 = C[3], na21 = C[4];
        const float b02 = C[5], b12 = C[6], b22 = C[7], na12 = C[8], na22 = C[9];
        const float g21 = C[10], g22 = C[11];

        // phase 1: zero-state pass of the fused pair; y2 in place, keep 4-state
        float s11 = 0.f, s12 = 0.f, s21 = 0.f, s22 = 0.f;
        #pragma unroll
        for (int t = 0; t < kChunk; ++t) {
            const float xv = x[t];
            const float y1 = fmaf(b01, xv, s11);
            const float t1 = fmaf(b11, xv, s12);
            s12 = fmaf(na21, y1, b21 * xv);
            s11 = fmaf(na11, y1, t1);
            const float y2 = fmaf(b02, y1, s21);
            const float t2 = fmaf(b12, y1, s22);
            s22 = fmaf(na22, y2, b22 * y1);
            s21 = fmaf(na12, y2, t2);
            x[t] = y2;
        }

        // exclusive shift (lane 0 -> zero state)
        float v1 = __shfl_up(s11, 1), v2 = __shfl_up(s12, 1);
        float v3 = __shfl_up(s21, 1), v4 = __shfl_up(s22, 1);
        if (lane == 0) { v1 = 0.f; v2 = 0.f; v3 = 0.f; v4 = 0.f; }

        // Kogge-Stone affine scan, 6 levels, 4-dim block-triangular apply
        #pragma unroll
        for (int j = 0; j < 6; ++j) {
            const int s = 1 << j;
            const float la1 = C[12 + 12 * j + 0], lb1 = C[12 + 12 * j + 1], lg1 = C[12 + 12 * j + 2];
            const float la2 = C[12 + 12 * j + 3], lb2 = C[12 + 12 * j + 4], lg2 = C[12 + 12 * j + 5];
            const float S00 = C[12 + 12 * j + 6], S01 = C[12 + 12 * j + 7];
            const float S10 = C[12 + 12 * j + 8], S11 = C[12 + 12 * j + 9];
            float t1 = __shfl_up(v1, (unsigned)s);
            float t2 = __shfl_up(v2, (unsigned)s);
            float t3 = __shfl_up(v3, (unsigned)s);
            float t4 = __shfl_up(v4, (unsigned)s);
            const bool ok = (lane >= s);
            t1 = ok ? t1 : 0.f; t2 = ok ? t2 : 0.f;
            t3 = ok ? t3 : 0.f; t4 = ok ? t4 : 0.f;
            // top band: v12 += (la1*A1 + lb1*I)*t12
            const float w1 = fmaf(na11, t1, t2);
            v1 = fmaf(la1, w1, fmaf(lb1, t1, v1));
            v2 = fmaf(lg1, t1, fmaf(lb1, t2, v2));
            // bottom band: v34 += (la2*A2 + lb2*I)*t34 + S*t12
            const float w2 = fmaf(na12, t3, t4);
            v3 = fmaf(la2, w2, fmaf(lb2, t3, fmaf(S00, t1, fmaf(S01, t2, v3))));
            v4 = fmaf(lg2, t3, fmaf(lb2, t4, fmaf(S10, t1, fmaf(S11, t2, v4))));
        }

        // phase 2: homogeneous correction of the pair
        float w11 = v1, w12 = v2, w21 = v3, w22 = v4;
        #pragma unroll
        for (int t = 0; t < kChunk; ++t) {
            x[t] += fmaf(b02, w11, w21);
            const float n11 = fmaf(na11, w11, w12);
            const float n12 = na21 * w11;
            const float n21 = fmaf(g21, w11, fmaf(na12, w21, w22));
            const float n22 = fmaf(g22, w11, na22 * w21);
            w11 = n11; w12 = n12; w21 = n21; w22 = n22;
        }
    }

    {
        float4* op = reinterpret_cast<float4*>(out + (size_t)ch * kFrame + lane * kChunk);
        #pragma unroll
        for (int k = 0; k < kChunk / 4; ++k) {
            float4 v;
            v.x = x[4 * k + 0]; v.y = x[4 * k + 1];
            v.z = x[4 * k + 2]; v.w = x[4 * k + 3];
            op[k] = v;
        }
    }
}

} // namespace

extern "C" void kernel_launch(void* const* d_in, const int* in_sizes, int n_in,
                              void* d_out, int out_size, void* d_ws, size_t ws_size,
                              hipStream_t stream)
{
    (void)in_sizes; (void)n_in; (void)ws_size;
    const float* audio  = (const float*)d_in[0];
    const float* params = (const float*)d_in[1];
    float* outp = (float*)d_out;
    float* ws   = (float*)d_ws;   // needs 2048*8*96*4 = 6.29 MB

    const int channels = out_size / kFrame;              // 2048
    const int jobs     = channels * kPairs;              // 16384
    hipLaunchKernelGGL(coef_kernel, dim3(jobs / 256), dim3(256), 0, stream,
                       params, ws);
    hipLaunchKernelGGL(biquad_main, dim3(channels / kWPB), dim3(256), 0, stream,
                       audio, ws, outp);
}

// Round 5
// 30.014 us; speedup vs baseline: 1.4232x; 1.4232x over previous
//
#include <hip/hip_runtime.h>
#include <math.h>

namespace {

constexpr int kNB    = 16;
constexpr int kFrame = 2048;
constexpr int kHalf  = 16;   // packed stream length (2 streams of 16 = 32/lane)
constexpr int kWPB   = 4;    // waves (= channels) per 256-thread block

typedef float f32x2 __attribute__((ext_vector_type(2)));

__device__ inline f32x2 pk_fma(f32x2 a, f32x2 b, f32x2 c) {
    f32x2 d;
    asm("v_pk_fma_f32 %0, %1, %2, %3" : "=v"(d) : "v"(a), "v"(b), "v"(c));
    return d;
}
__device__ inline f32x2 pk_mul(f32x2 a, f32x2 b) {
    f32x2 d;
    asm("v_pk_mul_f32 %0, %1, %2" : "=v"(d) : "v"(a), "v"(b));
    return d;
}
__device__ inline f32x2 pk_add(f32x2 a, f32x2 b) {
    f32x2 d;
    asm("v_pk_add_f32 %0, %1, %2" : "=v"(d) : "v"(a), "v"(b));
    return d;
}

__global__ __launch_bounds__(256)
void biquad_chain_kernel(const float* __restrict__ audio,
                         const float* __restrict__ params,
                         float* __restrict__ out)
{
    // per band: b0, b1, b2, -a1, -a2 (f32, broadband gains folded into b's)
    __shared__ float sC[kWPB][kNB][5];
    // per band, level L: A^(16*2^L) = alpha*A + beta*I, L=0..6 (A^16..A^1024)
    // [0]=alpha, [1]=beta, [2]=gamma=-a2*alpha
    __shared__ float sLvl[kWPB][kNB][7][3];

    const int tid  = threadIdx.x;
    const int wv   = tid >> 6;
    const int lane = tid & 63;
    const int ch   = blockIdx.x * kWPB + wv;   // 0..2047
    const int bb   = ch >> 7;                  // batch
    const int ff   = ch & 127;                 // frame

    const float* pb = params + (size_t)bb * (50 * 128) + ff;

    // ---- coefficient preamble: lane i -> band i; transcendentals UNIFORM ----
    if (lane < kNB) {
        const int band = lane;
        const double fn = (double)pb[(band * 3 + 0) * 128];
        const double gn = (double)pb[(band * 3 + 1) * 128];
        const double qn = (double)pb[(band * 3 + 2) * 128];
        const double PI   = 3.14159265358979323846;
        const double LN10 = 2.302585092994046;

        // per-band freq range (log-space), via cheap selects (uniform code path)
        // band 0: [20,500]; band 15: [5000,20000]; 1,14: [50,16000]; else [100,15000]
        const bool isHP = (band == 0), isLP = (band == kNB - 1);
        const bool isShelf = (band == 1) || (band == kNB - 2);
        const double flo = isHP ? 2.995732273553991
                        : isLP ? 8.517193191416238
                        : isShelf ? 3.912023005428146
                        : 4.605170185988092;
        const double fsp = isHP ? 3.2188758248682006
                        : isLP ? 1.3862943611198906
                        : isShelf ? 5.768320995793772
                        : 5.0106352940962555;

        // shared transcendental block (no divergence on the expensive part)
        const double Q  = exp(-0.6931471805599453 + qn * 3.4657359027997265);
        const double fc = exp(flo + fn * fsp);
        const double w0 = (2.0 * PI / 96000.0) * fc;
        const double sw = sin(w0);
        const double cw = cos(w0);
        const double al = sw / (2.0 * Q);
        const double gdb = (isHP || isLP) ? 0.0 : (-24.0 + gn * 48.0);
        const double A   = exp(gdb * (LN10 / 40.0));
        const double sA  = sqrt(A);
        // broadband in/out gain exponent (uniform exp; 1.0 for other lanes)
        const double ge = isHP ? (-60.0 + (double)pb[48 * 128] * 60.0) * (LN10 / 20.0)
                        : isLP ? (-60.0 + (double)pb[49 * 128] * 60.0) * (LN10 / 20.0)
                        : 0.0;
        const double gm = exp(ge);

        // cheap per-type coefficient assembly (FMAs only)
        double b0, b1, b2, a0, a1, a2;
        if (isHP) {
            b0 = (1.0 + cw) * 0.5; b1 = -(1.0 + cw); b2 = (1.0 + cw) * 0.5;
            a0 = 1.0 + al; a1 = -2.0 * cw; a2 = 1.0 - al;
        } else if (isLP) {
            b0 = (1.0 - cw) * 0.5; b1 = 1.0 - cw; b2 = (1.0 - cw) * 0.5;
            a0 = 1.0 + al; a1 = -2.0 * cw; a2 = 1.0 - al;
        } else if (band == 1) {                // low shelf
            const double s2 = 2.0 * sA * al;
            b0 = A * ((A + 1.0) - (A - 1.0) * cw + s2);
            b1 = 2.0 * A * ((A - 1.0) - (A + 1.0) * cw);
            b2 = A * ((A + 1.0) - (A - 1.0) * cw - s2);
            a0 = (A + 1.0) + (A - 1.0) * cw + s2;
            a1 = -2.0 * ((A - 1.0) + (A + 1.0) * cw);
            a2 = (A + 1.0) + (A - 1.0) * cw - s2;
        } else if (band == kNB - 2) {          // high shelf
            const double s2 = 2.0 * sA * al;
            b0 = A * ((A + 1.0) + (A - 1.0) * cw + s2);
            b1 = -2.0 * A * ((A - 1.0) + (A + 1.0) * cw);
            b2 = A * ((A + 1.0) + (A - 1.0) * cw - s2);
            a0 = (A + 1.0) - (A - 1.0) * cw + s2;
            a1 = 2.0 * ((A - 1.0) - (A + 1.0) * cw);
            a2 = (A + 1.0) - (A - 1.0) * cw - s2;
        } else {                               // peaking
            b0 = 1.0 + al * A; b1 = -2.0 * cw; b2 = 1.0 - al * A;
            a0 = 1.0 + al / A; a1 = -2.0 * cw; a2 = 1.0 - al / A;
        }
        const double inv  = 1.0 / a0;
        const double binv = inv * gm;          // fold broadband gain into b's
        b0 *= binv; b1 *= binv; b2 *= binv; a1 *= inv; a2 *= inv;

        sC[wv][band][0] = (float)b0;
        sC[wv][band][1] = (float)b1;
        sC[wv][band][2] = (float)b2;
        sC[wv][band][3] = (float)(-a1);
        sC[wv][band][4] = (float)(-a2);

        // Cayley-Hamilton power chain: A^k = al*A + be*I; doubling:
        // al' = al*(2*be - a1*al); be' = be*be - a2*al*al.
        // After doubling s (s=0..9): A^(2^(s+1)); store s=3..9 -> A^16..A^1024.
        double ap = 1.0, bp = 0.0;
        #pragma unroll
        for (int s = 0; s < 10; ++s) {
            const double an = ap * (2.0 * bp - a1 * ap);
            const double bn = bp * bp - a2 * (ap * ap);
            ap = an; bp = bn;
            if (s >= 3) {
                const int L = s - 3;
                sLvl[wv][band][L][0] = (float)ap;
                sLvl[wv][band][L][1] = (float)bp;
                sLvl[wv][band][L][2] = (float)(-a2 * ap);
            }
        }
    }
    __syncthreads();

    // ---- load 32 samples, pack as 2 streams of 16: X[t] = (x[t], x[t+16]) ----
    f32x2 X[kHalf];
    {
        const float4* ap = reinterpret_cast<const float4*>(
            audio + (size_t)ch * kFrame + lane * 32);
        #pragma unroll
        for (int k = 0; k < 4; ++k) {
            const float4 va = ap[k];        // samples 4k..4k+3
            const float4 vb = ap[k + 4];    // samples 16+4k..16+4k+3
            X[4 * k + 0] = f32x2{va.x, vb.x};
            X[4 * k + 1] = f32x2{va.y, vb.y};
            X[4 * k + 2] = f32x2{va.z, vb.z};
            X[4 * k + 3] = f32x2{va.w, vb.w};
        }
    }

    // ---- cascade ----
    for (int band = 0; band < kNB; ++band) {
        const float b0  = sC[wv][band][0];
        const float b1  = sC[wv][band][1];
        const float b2  = sC[wv][band][2];
        const float na1 = sC[wv][band][3];
        const float na2 = sC[wv][band][4];
        const f32x2 b0p  = {b0, b0},  b1p = {b1, b1}, b2p = {b2, b2};
        const f32x2 na1p = {na1, na1}, na2p = {na2, na2};

        // phase 1: two independent zero-state 16-sample streams (packed)
        f32x2 s1 = {0.f, 0.f}, s2 = {0.f, 0.f};
        #pragma unroll
        for (int t = 0; t < kHalf; ++t) {
            const f32x2 xv = X[t];
            const f32x2 y  = pk_fma(b0p, xv, s1);
            const f32x2 tm = pk_fma(b1p, xv, s2);
            s2 = pk_fma(na2p, y, pk_mul(b2p, xv));
            s1 = pk_fma(na1p, y, tm);
            X[t] = y;
        }

        // fold: dA = (s1.x, s2.x), dB = (s1.y, s2.y); d = A^16*dA + dB
        const float al16 = sLvl[wv][band][0][0];
        const float be16 = sLvl[wv][band][0][1];
        const float ga16 = sLvl[wv][band][0][2];
        const float wf = fmaf(na1, s1.x, s2.x);
        const float d0 = fmaf(al16, wf, fmaf(be16, s1.x, s1.y));
        const float d1 = fmaf(ga16, s1.x, fmaf(be16, s2.x, s2.y));

        // exclusive affine scan across 64 lanes (Kogge-Stone), M = A^32
        float v0, v1;
        {
            const float e0 = __shfl_up(d0, 1);
            const float e1 = __shfl_up(d1, 1);
            v0 = (lane == 0) ? 0.f : e0;
            v1 = (lane == 0) ? 0.f : e1;
        }
        #pragma unroll
        for (int j = 0; j < 6; ++j) {
            const int s = 1 << j;
            const float alpha = sLvl[wv][band][j + 1][0];
            const float beta  = sLvl[wv][band][j + 1][1];
            const float gamma = sLvl[wv][band][j + 1][2];
            float t0 = __shfl_up(v0, (unsigned)s);
            float t1 = __shfl_up(v1, (unsigned)s);
            const bool ok = (lane >= s);
            t0 = ok ? t0 : 0.f;
            t1 = ok ? t1 : 0.f;
            const float w = fmaf(na1, t0, t1);
            v0 = fmaf(alpha, w,  fmaf(beta, t0, v0));
            v1 = fmaf(gamma, t0, fmaf(beta, t1, v1));
        }

        // reconstruct: uA = v; uB = A^16*uA + dA
        const float wr  = fmaf(na1, v0, v1);
        const float uB0 = fmaf(al16, wr, fmaf(be16, v0, s1.x));
        const float uB1 = fmaf(ga16, v0, fmaf(be16, v1, s2.x));

        // phase 2: packed homogeneous correction  y(t) += [A^t * u]_0
        f32x2 w0 = {v0, uB0}, w1 = {v1, uB1};
        #pragma unroll
        for (int t = 0; t < kHalf; ++t) {
            const f32x2 c = w0;
            X[t] = pk_add(X[t], c);
            w0 = pk_fma(na1p, c, w1);
            w1 = pk_mul(na2p, c);
        }
    }

    // ---- unpack + store ----
    {
        float4* op = reinterpret_cast<float4*>(out + (size_t)ch * kFrame + lane * 32);
        #pragma unroll
        for (int k = 0; k < 4; ++k) {
            op[k]     = float4{X[4 * k + 0].x, X[4 * k + 1].x, X[4 * k + 2].x, X[4 * k + 3].x};
            op[k + 4] = float4{X[4 * k + 0].y, X[4 * k + 1].y, X[4 * k + 2].y, X[4 * k + 3].y};
        }
    }
}

} // namespace

extern "C" void kernel_launch(void* const* d_in, const int* in_sizes, int n_in,
                              void* d_out, int out_size, void* d_ws, size_t ws_size,
                              hipStream_t stream)
{
    (void)d_ws; (void)ws_size; (void)n_in; (void)in_sizes;
    const float* audio  = (const float*)d_in[0];
    const float* params = (const float*)d_in[1];
    float* outp = (float*)d_out;

    const int channels = out_size / kFrame;        // 2048
    const int blocks   = channels / kWPB;

    hipLaunchKernelGGL(biquad_chain_kernel, dim3(blocks), dim3(256), 0, stream,
                       audio, params, outp);
}